// Round 6
// baseline (233.555 us; speedup 1.0000x reference)
//
#include <hip/hip_runtime.h>
#include <hip/hip_bf16.h>
#include <cstdint>
#include <math.h>

#define BATCH 4
#define SDIM  2048
#define DDIM  1024
#define QKVN  3072   // fused Q|K|V output width

typedef __attribute__((ext_vector_type(8))) short bf16x8;
typedef __attribute__((ext_vector_type(8))) unsigned short u16x8;
typedef __attribute__((ext_vector_type(4))) float f32x4;

__device__ __forceinline__ float bf2f(unsigned short u) {
  union { unsigned int i; float f; } v; v.i = ((unsigned int)u) << 16; return v.f;
}
__device__ __forceinline__ unsigned short f2bf(float f) {
  unsigned int i = __float_as_uint(f);
  return (unsigned short)((i + 0x7FFFu + ((i >> 16) & 1u)) >> 16);  // RNE
}

#define GLOAD16(gp, lp) \
  __builtin_amdgcn_global_load_lds((const __attribute__((address_space(1))) void*)(gp), \
                                   (__attribute__((address_space(3))) void*)(lp), 16, 0, 0)

// ---------------- fp32 -> bf16 convert (single src) ----------------
__global__ void cvt_f32_bf16(const float* __restrict__ in,
                             unsigned short* __restrict__ out, int n) {
  int i0 = (blockIdx.x * 256 + threadIdx.x) * 4;
  int stride = gridDim.x * 256 * 4;
  for (int i = i0; i < n; i += stride) {
    float4 v = *reinterpret_cast<const float4*>(in + i);
    ushort4 o;
    o.x = f2bf(v.x); o.y = f2bf(v.y); o.z = f2bf(v.z); o.w = f2bf(v.w);
    *reinterpret_cast<ushort4*>(out + i) = o;
  }
}

// 4 weight matrices (1M elems each) in one dispatch; dsts contiguous slabs.
__global__ void cvt_weights(const float* __restrict__ s0, const float* __restrict__ s1,
                            const float* __restrict__ s2, const float* __restrict__ s3,
                            unsigned short* __restrict__ out) {
  const int NW = DDIM * DDIM;
  const float* src = (blockIdx.y == 0) ? s0 : (blockIdx.y == 1) ? s1
                    : (blockIdx.y == 2) ? s2 : s3;
  unsigned short* dst = out + (size_t)blockIdx.y * NW;
  int i0 = (blockIdx.x * 256 + threadIdx.x) * 4;
  int stride = gridDim.x * 256 * 4;
  for (int i = i0; i < NW; i += stride) {
    float4 v = *reinterpret_cast<const float4*>(src + i);
    ushort4 o;
    o.x = f2bf(v.x); o.y = f2bf(v.y); o.z = f2bf(v.z); o.w = f2bf(v.w);
    *reinterpret_cast<ushort4*>(dst + i) = o;
  }
}

// ========== WIDE engine: 128x256 block, 4 waves, wave tile 64x128 ============
// Tri-buffered (proven R3 schedule), BK=32, counted vmcnt(6), K=1024.
// LDS 72 KB: As 3x[128x32]=24KB, Bs 3x[256x32]=48KB -> 2 blocks/CU.
// Per wave K-step: 4 A-frag + 8 B-frag ds_read_b128 feed 32 MFMA ->
//   LDS bytes/FLOP 25% lower than the 64x64 engine (LDS was the binding pole).
// Swizzle per slab (row-periodic, works for 128 or 256 rows):
//   unit u=row>>1, granule g=(row&1)*4+slot16, phys p = g ^ (u&7).
// MODE 0: QKV  A=xb[8192,1024] B=Wqkv[3072,1024] C=bf16[8192,3072]+bias(tj>>2)
// MODE 1: outp A=Ob[8192,1024] B=Wo[1024,1024]   C=f32[8192,1024]+bias
template<int MODE>
__global__ __launch_bounds__(256, 2)
void gemm_wide(const unsigned short* __restrict__ A,
               const unsigned short* __restrict__ B,
               const float* __restrict__ bias0,
               const float* __restrict__ bias1,
               const float* __restrict__ bias2,
               void* __restrict__ C)
{
  __shared__ unsigned short As[3][4096];   // 3 x 8 KB  (128r x 32c)
  __shared__ unsigned short Bs[3][8192];   // 3 x 16 KB (256r x 32c)

  constexpr int LDK = 1024;
  constexpr int CLD = (MODE == 0) ? QKVN : DDIM;
  constexpr int KT  = 32;                  // K / 32

  const int ti = blockIdx.x;               // 0..63   (128-row A tile)
  const int tj = blockIdx.y;               // 0..11/3 (256-row B tile)

  const int tid  = threadIdx.x;
  const int wave = tid >> 6;
  const int lane = tid & 63;
  const int wm   = wave >> 1;              // M half (0..1): rows wm*64
  const int wn   = wave & 1;               // N half (0..1): cols wn*128

  const unsigned short* Ab = A + (size_t)ti * 128 * LDK;
  const unsigned short* Bb = B + (size_t)tj * 256 * LDK;

  // staging per-lane source coords (inverse swizzle; LDS dest linear)
  const int g0   = (lane & 7) ^ (lane >> 3);
  const int rloc = 2 * (lane >> 3) + (g0 >> 2);   // row within 16-row chunk
  const int colg = (g0 & 3) * 8;                  // elem col within 32-col tile

  // fragment read offsets (swizzled)
  const int s_ = lane >> 4;
  const int fr = lane & 15;
  const int p_ = (((fr & 1) << 2) | s_) ^ ((fr >> 1) & 7);
  const int fA = wm * 2048 + (fr >> 1) * 64 + p_ * 8;   // + m*512
  const int fB = wn * 4096 + (fr >> 1) * 64 + p_ * 8;   // + n*512

  f32x4 acc[4][8];
#pragma unroll
  for (int i = 0; i < 4; ++i)
#pragma unroll
    for (int j = 0; j < 8; ++j) acc[i][j] = (f32x4){0.f, 0.f, 0.f, 0.f};

#define STAGEW(buf, kt) do {                                                               \
    const size_t kb_ = (size_t)(kt) * 32 + colg;                                           \
    GLOAD16(Ab + (size_t)(wave * 16 + rloc) * LDK + kb_,       &As[buf][wave * 512]);       \
    GLOAD16(Ab + (size_t)(64 + wave * 16 + rloc) * LDK + kb_,  &As[buf][2048 + wave * 512]);\
    GLOAD16(Bb + (size_t)(wave * 16 + rloc) * LDK + kb_,       &Bs[buf][wave * 512]);       \
    GLOAD16(Bb + (size_t)(64 + wave * 16 + rloc) * LDK + kb_,  &Bs[buf][2048 + wave * 512]);\
    GLOAD16(Bb + (size_t)(128 + wave * 16 + rloc) * LDK + kb_, &Bs[buf][4096 + wave * 512]);\
    GLOAD16(Bb + (size_t)(192 + wave * 16 + rloc) * LDK + kb_, &Bs[buf][6144 + wave * 512]);\
  } while (0)

  STAGEW(0, 0);
  STAGEW(1, 1);
  asm volatile("s_waitcnt vmcnt(6)" ::: "memory");   // drain tile0; leave tile1
  __builtin_amdgcn_s_barrier();
  __builtin_amdgcn_sched_barrier(0);

  for (int kt = 0; kt < KT; ++kt) {
    const int cur = kt % 3;
    const bool st = (kt + 2 < KT);
    if (st) STAGEW((kt + 2) % 3, kt + 2);

    bf16x8 af[4], bg[8];
#pragma unroll
    for (int m = 0; m < 4; ++m)
      af[m] = *reinterpret_cast<const bf16x8*>(&As[cur][fA + m * 512]);
#pragma unroll
    for (int n = 0; n < 8; ++n)
      bg[n] = *reinterpret_cast<const bf16x8*>(&Bs[cur][fB + n * 512]);

    __builtin_amdgcn_s_setprio(1);
#pragma unroll
    for (int m = 0; m < 4; ++m)
#pragma unroll
      for (int n = 0; n < 8; ++n)
        acc[m][n] = __builtin_amdgcn_mfma_f32_16x16x32_bf16(af[m], bg[n], acc[m][n], 0, 0, 0);
    __builtin_amdgcn_s_setprio(0);

    // drain tile kt+1 (leave kt+2 in flight); tail iters drain fully (race fix)
    if (st) { asm volatile("s_waitcnt vmcnt(6)" ::: "memory"); }
    else    { asm volatile("s_waitcnt vmcnt(0)" ::: "memory"); }
    __builtin_amdgcn_s_barrier();
    __builtin_amdgcn_sched_barrier(0);
  }
#undef STAGEW

  // epilogue: C/D layout col = lane&15, row = (lane>>4)*4 + r
  const int row0 = ti * 128 + wm * 64;
  const int col0 = tj * 256 + wn * 128;
  const float* bp = bias0;
  if constexpr (MODE == 0) bp = (tj < 4) ? bias0 : ((tj < 8) ? bias1 : bias2);
#pragma unroll
  for (int m = 0; m < 4; ++m) {
#pragma unroll
    for (int n = 0; n < 8; ++n) {
#pragma unroll
      for (int r = 0; r < 4; ++r) {
        const int gr = row0 + m * 16 + (lane >> 4) * 4 + r;
        const int gc = col0 + n * 16 + (lane & 15);
        const float v = acc[m][n][r];
        if constexpr (MODE == 0) {
          ((unsigned short*)C)[(size_t)gr * CLD + gc] = f2bf(v + bp[gc & 1023]);
        } else {
          ((float*)C)[(size_t)gr * CLD + gc] = v + bp[gc];
        }
      }
    }
  }
}

// ============== 128x128 tri-buffered GEMM (R3 engine, scores/PV) =============
// MODE 2: scores: per-batch triangular grid; A=Q sec, B=K sec of QKVb (ld 3072)
// MODE 3: PV: per-batch, A=P[b][2048,2048], B=Vt[b][1024,2048], K truncated
template<int MODE>
__global__ __launch_bounds__(256, 3)
void gemm_kernel(const unsigned short* __restrict__ A,
                 const unsigned short* __restrict__ B,
                 void* __restrict__ C)
{
  __shared__ unsigned short As[3][128 * 32];
  __shared__ unsigned short Bs[3][128 * 32];

  const int tid  = threadIdx.x;
  const int wave = tid >> 6;
  const int lane = tid & 63;
  const int wr   = wave >> 1;
  const int wc   = wave & 1;

  const unsigned short *Ab, *Bb;
  int lda, ldb, ktiles;
  int ti, tj, bz = 0;

  if constexpr (MODE == 2) {
    int t = blockIdx.x; bz = blockIdx.y;
    ti = 0;
    while ((ti + 1) * (ti + 2) / 2 <= t) ++ti;   // triangular decode
    tj = t - ti * (ti + 1) / 2;                  // tj <= ti
    Ab = A + (size_t)bz * SDIM * QKVN + (size_t)ti * 128 * QKVN;        lda = QKVN; // Q
    Bb = A + (size_t)bz * SDIM * QKVN + (size_t)tj * 128 * QKVN + 1024; ldb = QKVN; // K
    ktiles = DDIM / 32;
  } else { // MODE 3
    bz = blockIdx.y;
    ti = blockIdx.x >> 3;
    tj = blockIdx.x & 7;
    Ab = A + (size_t)bz * SDIM * SDIM + (size_t)ti * 128 * SDIM; lda = SDIM;
    Bb = B + (size_t)bz * DDIM * SDIM + (size_t)tj * 128 * SDIM; ldb = SDIM;
    ktiles = (ti + 1) * 4;
  }

  f32x4 acc[4][4];
#pragma unroll
  for (int i = 0; i < 4; ++i)
#pragma unroll
    for (int j = 0; j < 4; ++j) acc[i][j] = (f32x4){0.f, 0.f, 0.f, 0.f};

  const int g0   = (lane & 7) ^ (lane >> 3);
  const int rloc = 2 * (lane >> 3) + (g0 >> 2);
  const int colg = (g0 & 3) * 8;

  const int s_  = lane >> 4;
  const int fr  = lane & 15;
  const int p_  = (((fr & 1) << 2) | s_) ^ ((fr >> 1) & 7);
  const int fA  = wr * 2048 + (fr >> 1) * 64 + p_ * 8;
  const int fB  = wc * 2048 + (fr >> 1) * 64 + p_ * 8;

#define STAGE(buf, kt) do {                                                     \
    const size_t kb_ = (size_t)(kt) * 32 + colg;                                \
    GLOAD16(Ab + (size_t)(wave * 16 + rloc) * lda + kb_,      &As[buf][wave * 512]);       \
    GLOAD16(Ab + (size_t)(64 + wave * 16 + rloc) * lda + kb_, &As[buf][(wave + 4) * 512]); \
    GLOAD16(Bb + (size_t)(wave * 16 + rloc) * ldb + kb_,      &Bs[buf][wave * 512]);       \
    GLOAD16(Bb + (size_t)(64 + wave * 16 + rloc) * ldb + kb_, &Bs[buf][(wave + 4) * 512]); \
  } while (0)

  STAGE(0, 0);
  STAGE(1, 1);
  asm volatile("s_waitcnt vmcnt(4)" ::: "memory");
  __builtin_amdgcn_s_barrier();
  __builtin_amdgcn_sched_barrier(0);

  for (int kt = 0; kt < ktiles; ++kt) {
    const int cur = kt % 3;
    const bool st = (kt + 2 < ktiles);
    if (st) STAGE((kt + 2) % 3, kt + 2);

    bf16x8 af[4], bfv[4];
#pragma unroll
    for (int mi = 0; mi < 4; ++mi)
      af[mi] = *reinterpret_cast<const bf16x8*>(&As[cur][fA + mi * 512]);
#pragma unroll
    for (int ni = 0; ni < 4; ++ni)
      bfv[ni] = *reinterpret_cast<const bf16x8*>(&Bs[cur][fB + ni * 512]);

    __builtin_amdgcn_s_setprio(1);
#pragma unroll
    for (int mi = 0; mi < 4; ++mi)
#pragma unroll
      for (int ni = 0; ni < 4; ++ni)
        acc[mi][ni] = __builtin_amdgcn_mfma_f32_16x16x32_bf16(af[mi], bfv[ni], acc[mi][ni], 0, 0, 0);
    __builtin_amdgcn_s_setprio(0);

    // tail iters drain fully (race fix: tile kt+1 must be resident next iter)
    if (st) { asm volatile("s_waitcnt vmcnt(4)" ::: "memory"); }
    else    { asm volatile("s_waitcnt vmcnt(0)" ::: "memory"); }
    __builtin_amdgcn_s_barrier();
    __builtin_amdgcn_sched_barrier(0);
  }
#undef STAGE

  const int row0 = wr * 64, col0 = wc * 64;
#pragma unroll
  for (int mi = 0; mi < 4; ++mi) {
#pragma unroll
    for (int ni = 0; ni < 4; ++ni) {
#pragma unroll
      for (int r = 0; r < 4; ++r) {
        const int lr = row0 + mi * 16 + (lane >> 4) * 4 + r;
        const int lc = col0 + ni * 16 + (lane & 15);
        const float v = acc[mi][ni][r];
        if constexpr (MODE == 2) {
          const int gi = ti * 128 + lr, gj = tj * 128 + lc;
          float s = fabsf(v) * 0.03125f;            // |q.k| / sqrt(1024)
          if (gj > gi) s = -INFINITY;               // strictly-above diag
          ((unsigned short*)C)[(size_t)bz * SDIM * SDIM + (size_t)gi * SDIM + gj] = f2bf(s);
        } else {
          const int gi = ti * 128 + lr, gd = tj * 128 + lc;
          ((unsigned short*)C)[(size_t)bz * SDIM * DDIM + (size_t)gi * DDIM + gd] = f2bf(v);
        }
      }
    }
  }
}

// ---------------- one-pass vectorized row softmax ----------------
__global__ void softmax_rows(unsigned short* __restrict__ Sc) {
  const int rid = blockIdx.x;
  const int b = rid >> 11, i = rid & (SDIM - 1);
  unsigned short* row = Sc + ((size_t)b * SDIM + i) * SDIM;
  const int Lpad = ((i >> 7) + 1) << 7;  // next 128 boundary (PV is 128-tiled)
  const int tid  = threadIdx.x;
  const bool act = tid * 8 < Lpad;

  float v[8];
  float m = 0.0f;
  if (act) {
    u16x8 u = *reinterpret_cast<const u16x8*>(row + tid * 8);
#pragma unroll
    for (int e = 0; e < 8; ++e) { v[e] = bf2f(u[e]); m = fmaxf(m, v[e]); }
  }
#pragma unroll
  for (int off = 32; off; off >>= 1) m = fmaxf(m, __shfl_down(m, off));
  __shared__ float redm[4], reds[4];
  if ((tid & 63) == 0) redm[tid >> 6] = m;
  __syncthreads();
  const float M = fmaxf(fmaxf(redm[0], redm[1]), fmaxf(redm[2], redm[3]));

  float s = 0.0f;
  if (act) {
#pragma unroll
    for (int e = 0; e < 8; ++e) { v[e] = expf(v[e] - M); s += v[e]; }
  }
#pragma unroll
  for (int off = 32; off; off >>= 1) s += __shfl_down(s, off);
  if ((tid & 63) == 0) reds[tid >> 6] = s;
  __syncthreads();
  const float inv = 1.0f / (reds[0] + reds[1] + reds[2] + reds[3]);

  if (act) {
    ushort4 o0, o1;
    o0.x = f2bf(v[0] * inv); o0.y = f2bf(v[1] * inv);
    o0.z = f2bf(v[2] * inv); o0.w = f2bf(v[3] * inv);
    o1.x = f2bf(v[4] * inv); o1.y = f2bf(v[5] * inv);
    o1.z = f2bf(v[6] * inv); o1.w = f2bf(v[7] * inv);
    *reinterpret_cast<ushort4*>(row + tid * 8)     = o0;
    *reinterpret_cast<ushort4*>(row + tid * 8 + 4) = o1;
  }
}

// ---------------- bf16 transpose: V section of QKVb -> Vt[B,1024,2048] -------
__global__ void transpose_v(const unsigned short* __restrict__ qkv,
                            unsigned short* __restrict__ out) {
  __shared__ unsigned short tile[64][65];
  const int b = blockIdx.z;
  const unsigned short* in = qkv + (size_t)b * SDIM * QKVN + 2048;  // V section
  unsigned short* o = out + (size_t)b * DDIM * SDIM;
  const int tx = threadIdx.x & 63;
  const int ty = threadIdx.x >> 6;
  const int r0 = blockIdx.y * 64;
  const int c0 = blockIdx.x * 64;
  for (int r = ty; r < 64; r += 4)
    tile[r][tx] = in[(size_t)(r0 + r) * QKVN + c0 + tx];
  __syncthreads();
  for (int r = ty; r < 64; r += 4)
    o[(size_t)(c0 + r) * SDIM + r0 + tx] = tile[tx][r];
}

// ---------------- host launch ----------------
extern "C" void kernel_launch(void* const* d_in, const int* in_sizes, int n_in,
                              void* d_out, int out_size, void* d_ws, size_t ws_size,
                              hipStream_t stream) {
  const float* x  = (const float*)d_in[0];
  const float* Wq = (const float*)d_in[1];
  const float* bq = (const float*)d_in[2];
  const float* Wk = (const float*)d_in[3];
  const float* bk = (const float*)d_in[4];
  const float* Wv = (const float*)d_in[5];
  const float* bv = (const float*)d_in[6];
  const float* Wo = (const float*)d_in[7];
  const float* bo = (const float*)d_in[8];
  float* out = (float*)d_out;

  const size_t NTOK = (size_t)BATCH * SDIM;       // 8192
  unsigned short* ws = (unsigned short*)d_ws;
  unsigned short* xb   = ws;                          // [8192,1024]
  unsigned short* wqkv = xb + NTOK * DDIM;            // [3072,1024]
  unsigned short* wo   = wqkv + (size_t)QKVN * DDIM;  // [1024,1024]
  unsigned short* QKVb = wo + (size_t)DDIM * DDIM;    // [8192,3072]
  unsigned short* Vt   = QKVb + NTOK * QKVN;          // [B,1024,2048]
  unsigned short* Ob   = Vt + NTOK * DDIM;            // [8192,1024]
  unsigned short* Sc   = Ob + NTOK * DDIM;            // [B,2048,2048]

  const int NX = (int)(NTOK * DDIM);              // 8M

  cvt_f32_bf16<<<2048, 256, 0, stream>>>(x, xb, NX);
  cvt_weights<<<dim3(256, 4), 256, 0, stream>>>(Wq, Wk, Wv, Wo, wqkv);

  // fused QKV projection -> QKVb [8192, 3072]  (64 x 12 blocks, 2/CU)
  gemm_wide<0><<<dim3(64, 12), 256, 0, stream>>>(xb, wqkv, bq, bk, bv, QKVb);

  // scores (lower-triangular tiles): Sc = bf16(|Q@K^T|/32), -inf above diag
  gemm_kernel<2><<<dim3(136, BATCH), 256, 0, stream>>>(QKVb, nullptr, Sc);

  // one-pass softmax (in place; padding becomes exact 0)
  softmax_rows<<<BATCH * SDIM, 256, 0, stream>>>(Sc);

  // V transpose for NT PV gemm
  transpose_v<<<dim3(DDIM / 64, SDIM / 64, BATCH), 256, 0, stream>>>(QKVb, Vt);

  // O = P @ V (causal-truncated K)
  gemm_kernel<3><<<dim3(128, BATCH), 256, 0, stream>>>(Sc, Vt, Ob);

  // final projection -> fp32 out  (64 x 4 blocks)
  gemm_wide<1><<<dim3(64, 4), 256, 0, stream>>>(Ob, wo, bo, nullptr, nullptr, out);
}

// Round 7
// 212.019 us; speedup vs baseline: 1.1016x; 1.1016x over previous
//
#include <hip/hip_runtime.h>
#include <hip/hip_bf16.h>
#include <cstdint>
#include <math.h>

#define BATCH 4
#define SDIM  2048
#define DDIM  1024
#define QKVN  3072   // fused Q|K|V output width

typedef __attribute__((ext_vector_type(8))) short bf16x8;
typedef __attribute__((ext_vector_type(8))) unsigned short u16x8;
typedef __attribute__((ext_vector_type(4))) float f32x4;

__device__ __forceinline__ float bf2f(unsigned short u) {
  union { unsigned int i; float f; } v; v.i = ((unsigned int)u) << 16; return v.f;
}
__device__ __forceinline__ unsigned short f2bf(float f) {
  unsigned int i = __float_as_uint(f);
  return (unsigned short)((i + 0x7FFFu + ((i >> 16) & 1u)) >> 16);  // RNE
}

#define GLOAD16(gp, lp) \
  __builtin_amdgcn_global_load_lds((const __attribute__((address_space(1))) void*)(gp), \
                                   (__attribute__((address_space(3))) void*)(lp), 16, 0, 0)

// ---------------- fp32 -> bf16 convert (single src) ----------------
__global__ void cvt_f32_bf16(const float* __restrict__ in,
                             unsigned short* __restrict__ out, int n) {
  int i0 = (blockIdx.x * 256 + threadIdx.x) * 4;
  int stride = gridDim.x * 256 * 4;
  for (int i = i0; i < n; i += stride) {
    float4 v = *reinterpret_cast<const float4*>(in + i);
    ushort4 o;
    o.x = f2bf(v.x); o.y = f2bf(v.y); o.z = f2bf(v.z); o.w = f2bf(v.w);
    *reinterpret_cast<ushort4*>(out + i) = o;
  }
}

// 4 weight matrices (1M elems each) in one dispatch; dsts contiguous slabs.
__global__ void cvt_weights(const float* __restrict__ s0, const float* __restrict__ s1,
                            const float* __restrict__ s2, const float* __restrict__ s3,
                            unsigned short* __restrict__ out) {
  const int NW = DDIM * DDIM;
  const float* src = (blockIdx.y == 0) ? s0 : (blockIdx.y == 1) ? s1
                    : (blockIdx.y == 2) ? s2 : s3;
  unsigned short* dst = out + (size_t)blockIdx.y * NW;
  int i0 = (blockIdx.x * 256 + threadIdx.x) * 4;
  int stride = gridDim.x * 256 * 4;
  for (int i = i0; i < NW; i += stride) {
    float4 v = *reinterpret_cast<const float4*>(src + i);
    ushort4 o;
    o.x = f2bf(v.x); o.y = f2bf(v.y); o.z = f2bf(v.z); o.w = f2bf(v.w);
    *reinterpret_cast<ushort4*>(dst + i) = o;
  }
}

// ============ 128x128 tri-buffered MFMA GEMM (proven R3 engine) ==============
// NT: C[m,n] = sum_k A[m,k]*B[n,k]; A,B row-major bf16, K contiguous.
// Tri-buffer BK=32 schedule, counted vmcnt(4) (tail iters drain 0), zero-
// conflict row-pair XOR swizzle (measured: SQ_LDS_BANK_CONFLICT = 0).
// MODE 0: QKV: A=xb[8192,1024] B=Wqkv[3072,1024] C=bf16[8192,3072]+bias(sel)
// MODE 1: out: A=Ob[8192,1024] B=Wo[1024,1024]   C=f32[8192,1024]+bias
// MODE 2: scores: per-batch triangular grid; writes P=exp(|qk|/32) (0 above
//         diag) and per-row partial sums -> aux[row*32 + tj*2 + wc]
// MODE 3: PV: per-batch, A=P[b][2048,2048], B=Vt[b][1024,2048], K truncated;
//         epilogue multiplies by aux=rowInv
template<int MODE>
__global__ __launch_bounds__(256, 3)
void gemm_kernel(const unsigned short* __restrict__ A,
                 const unsigned short* __restrict__ B,
                 const float* __restrict__ bias0,
                 const float* __restrict__ bias1,
                 const float* __restrict__ bias2,
                 float* __restrict__ aux,
                 void* __restrict__ C)
{
  __shared__ unsigned short As[3][128 * 32];
  __shared__ unsigned short Bs[3][128 * 32];

  const int tid  = threadIdx.x;
  const int wave = tid >> 6;
  const int lane = tid & 63;
  const int wr   = wave >> 1;
  const int wc   = wave & 1;

  const unsigned short *Ab, *Bb;
  int lda, ldb, ktiles;
  int ti, tj, bz = 0;

  if constexpr (MODE == 0 || MODE == 1) {
    ti = blockIdx.x; tj = blockIdx.y;
    Ab = A + (size_t)ti * 128 * DDIM;  lda = DDIM;
    Bb = B + (size_t)tj * 128 * DDIM;  ldb = DDIM;
    ktiles = DDIM / 32;
  } else if constexpr (MODE == 2) {
    int t = blockIdx.x; bz = blockIdx.y;
    ti = 0;
    while ((ti + 1) * (ti + 2) / 2 <= t) ++ti;   // triangular decode
    tj = t - ti * (ti + 1) / 2;                  // tj <= ti
    Ab = A + (size_t)bz * SDIM * QKVN + (size_t)ti * 128 * QKVN;        lda = QKVN; // Q
    Bb = A + (size_t)bz * SDIM * QKVN + (size_t)tj * 128 * QKVN + 1024; ldb = QKVN; // K
    ktiles = DDIM / 32;
  } else { // MODE 3
    bz = blockIdx.y;
    ti = blockIdx.x >> 3;
    tj = blockIdx.x & 7;
    Ab = A + (size_t)bz * SDIM * SDIM + (size_t)ti * 128 * SDIM; lda = SDIM;
    Bb = B + (size_t)bz * DDIM * SDIM + (size_t)tj * 128 * SDIM; ldb = SDIM;
    ktiles = (ti + 1) * 4;
  }

  f32x4 acc[4][4];
#pragma unroll
  for (int i = 0; i < 4; ++i)
#pragma unroll
    for (int j = 0; j < 4; ++j) acc[i][j] = (f32x4){0.f, 0.f, 0.f, 0.f};

  const int g0   = (lane & 7) ^ (lane >> 3);
  const int rloc = 2 * (lane >> 3) + (g0 >> 2);
  const int colg = (g0 & 3) * 8;

  const int s_  = lane >> 4;
  const int fr  = lane & 15;
  const int p_  = (((fr & 1) << 2) | s_) ^ ((fr >> 1) & 7);
  const int fA  = wr * 2048 + (fr >> 1) * 64 + p_ * 8;
  const int fB  = wc * 2048 + (fr >> 1) * 64 + p_ * 8;

#define STAGE(buf, kt) do {                                                     \
    const size_t kb_ = (size_t)(kt) * 32 + colg;                                \
    GLOAD16(Ab + (size_t)(wave * 16 + rloc) * lda + kb_,      &As[buf][wave * 512]);       \
    GLOAD16(Ab + (size_t)(64 + wave * 16 + rloc) * lda + kb_, &As[buf][(wave + 4) * 512]); \
    GLOAD16(Bb + (size_t)(wave * 16 + rloc) * ldb + kb_,      &Bs[buf][wave * 512]);       \
    GLOAD16(Bb + (size_t)(64 + wave * 16 + rloc) * ldb + kb_, &Bs[buf][(wave + 4) * 512]); \
  } while (0)

  STAGE(0, 0);
  STAGE(1, 1);
  asm volatile("s_waitcnt vmcnt(4)" ::: "memory");
  __builtin_amdgcn_s_barrier();
  __builtin_amdgcn_sched_barrier(0);

  for (int kt = 0; kt < ktiles; ++kt) {
    const int cur = kt % 3;
    const bool st = (kt + 2 < ktiles);
    if (st) STAGE((kt + 2) % 3, kt + 2);

    bf16x8 af[4], bfv[4];
#pragma unroll
    for (int mi = 0; mi < 4; ++mi)
      af[mi] = *reinterpret_cast<const bf16x8*>(&As[cur][fA + mi * 512]);
#pragma unroll
    for (int ni = 0; ni < 4; ++ni)
      bfv[ni] = *reinterpret_cast<const bf16x8*>(&Bs[cur][fB + ni * 512]);

    __builtin_amdgcn_s_setprio(1);
#pragma unroll
    for (int mi = 0; mi < 4; ++mi)
#pragma unroll
      for (int ni = 0; ni < 4; ++ni)
        acc[mi][ni] = __builtin_amdgcn_mfma_f32_16x16x32_bf16(af[mi], bfv[ni], acc[mi][ni], 0, 0, 0);
    __builtin_amdgcn_s_setprio(0);

    // tail iters drain fully (tile kt+1 must be resident next iter)
    if (st) { asm volatile("s_waitcnt vmcnt(4)" ::: "memory"); }
    else    { asm volatile("s_waitcnt vmcnt(0)" ::: "memory"); }
    __builtin_amdgcn_s_barrier();
    __builtin_amdgcn_sched_barrier(0);
  }
#undef STAGE

  // epilogue: C/D layout col = lane&15, row = (lane>>4)*4 + r
  const int row0 = wr * 64, col0 = wc * 64;
  const float* bp = bias0;
  if constexpr (MODE == 0) bp = (tj < 8) ? bias0 : ((tj < 16) ? bias1 : bias2);

  if constexpr (MODE == 2) {
    // P = exp(|s|/32), 0 strictly above diag; accumulate per-row partial sums
    // of the bf16-ROUNDED values (matches what PV will consume).
#pragma unroll
    for (int mi = 0; mi < 4; ++mi) {
#pragma unroll
      for (int r = 0; r < 4; ++r) {
        const int gi = ti * 128 + row0 + mi * 16 + (lane >> 4) * 4 + r;
        float ps = 0.f;
#pragma unroll
        for (int ni = 0; ni < 4; ++ni) {
          const int gj = tj * 128 + col0 + ni * 16 + (lane & 15);
          float p = (gj > gi) ? 0.f : expf(fabsf(acc[mi][ni][r]) * 0.03125f);
          unsigned short us = f2bf(p);
          ((unsigned short*)C)[(size_t)bz * SDIM * SDIM + (size_t)gi * SDIM + gj] = us;
          ps += bf2f(us);
        }
        // reduce across the 16 lanes sharing this row (lane bits 0..3)
        ps += __shfl_xor(ps, 1);
        ps += __shfl_xor(ps, 2);
        ps += __shfl_xor(ps, 4);
        ps += __shfl_xor(ps, 8);
        if ((lane & 15) == 0)
          aux[((size_t)bz * SDIM + gi) * 32 + tj * 2 + wc] = ps;
      }
    }
  } else {
#pragma unroll
    for (int mi = 0; mi < 4; ++mi) {
#pragma unroll
      for (int ni = 0; ni < 4; ++ni) {
#pragma unroll
        for (int r = 0; r < 4; ++r) {
          const int lr = row0 + mi * 16 + (lane >> 4) * 4 + r;
          const int lc = col0 + ni * 16 + (lane & 15);
          const float v = acc[mi][ni][r];
          if constexpr (MODE == 0) {
            const int gr = ti * 128 + lr, gc = tj * 128 + lc;
            ((unsigned short*)C)[(size_t)gr * QKVN + gc] = f2bf(v + bp[gc & 1023]);
          } else if constexpr (MODE == 1) {
            const int gr = ti * 128 + lr, gc = tj * 128 + lc;
            ((float*)C)[(size_t)gr * DDIM + gc] = v + bp[gc];
          } else { // MODE 3: normalize by row reciprocal
            const int gi = ti * 128 + lr, gd = tj * 128 + lc;
            const float inv = aux[(size_t)bz * SDIM + gi];
            ((unsigned short*)C)[(size_t)bz * SDIM * DDIM + (size_t)gi * DDIM + gd] = f2bf(v * inv);
          }
        }
      }
    }
  }
}

// ---------------- row reciprocal: rowInv = 1 / sum(partials) -----------------
// partial[rid][32]: slots tj*2+wc, tj = 0..(i>>7). Fixed-order sum -> deterministic.
__global__ void row_recip(const float* __restrict__ partial,
                          float* __restrict__ rowInv) {
  const int rid = blockIdx.x * 256 + threadIdx.x;   // 0 .. BATCH*SDIM-1
  const int i = rid & (SDIM - 1);
  const int n = ((i >> 7) + 1) * 2;
  const float* p = partial + (size_t)rid * 32;
  float s = 0.f;
  for (int j = 0; j < n; ++j) s += p[j];
  rowInv[rid] = 1.0f / s;                           // s >= exp(0) = 1 > 0
}

// ---------------- bf16 transpose: V section of QKVb -> Vt[B,1024,2048] -------
__global__ void transpose_v(const unsigned short* __restrict__ qkv,
                            unsigned short* __restrict__ out) {
  __shared__ unsigned short tile[64][65];
  const int b = blockIdx.z;
  const unsigned short* in = qkv + (size_t)b * SDIM * QKVN + 2048;  // V section
  unsigned short* o = out + (size_t)b * DDIM * SDIM;
  const int tx = threadIdx.x & 63;
  const int ty = threadIdx.x >> 6;
  const int r0 = blockIdx.y * 64;
  const int c0 = blockIdx.x * 64;
  for (int r = ty; r < 64; r += 4)
    tile[r][tx] = in[(size_t)(r0 + r) * QKVN + c0 + tx];
  __syncthreads();
  for (int r = ty; r < 64; r += 4)
    o[(size_t)(c0 + r) * SDIM + r0 + tx] = tile[tx][r];
}

// ---------------- host launch ----------------
extern "C" void kernel_launch(void* const* d_in, const int* in_sizes, int n_in,
                              void* d_out, int out_size, void* d_ws, size_t ws_size,
                              hipStream_t stream) {
  const float* x  = (const float*)d_in[0];
  const float* Wq = (const float*)d_in[1];
  const float* bq = (const float*)d_in[2];
  const float* Wk = (const float*)d_in[3];
  const float* bk = (const float*)d_in[4];
  const float* Wv = (const float*)d_in[5];
  const float* bv = (const float*)d_in[6];
  const float* Wo = (const float*)d_in[7];
  const float* bo = (const float*)d_in[8];
  float* out = (float*)d_out;

  const size_t NTOK = (size_t)BATCH * SDIM;       // 8192
  unsigned short* ws = (unsigned short*)d_ws;
  unsigned short* xb   = ws;                          // [8192,1024]
  unsigned short* wqkv = xb + NTOK * DDIM;            // [3072,1024]
  unsigned short* wo   = wqkv + (size_t)QKVN * DDIM;  // [1024,1024]
  unsigned short* QKVb = wo + (size_t)DDIM * DDIM;    // [8192,3072]
  unsigned short* Vt   = QKVb + NTOK * QKVN;          // [B,1024,2048]
  unsigned short* Ob   = Vt + NTOK * DDIM;            // [8192,1024]
  unsigned short* Sc   = Ob + NTOK * DDIM;            // [B,2048,2048] = P (exp)
  float* partial = (float*)(Sc + (size_t)BATCH * SDIM * SDIM);  // [8192][32]
  float* rowInv  = partial + NTOK * 32;                          // [8192]

  const int NX = (int)(NTOK * DDIM);              // 8M

  cvt_f32_bf16<<<2048, 256, 0, stream>>>(x, xb, NX);
  cvt_weights<<<dim3(256, 4), 256, 0, stream>>>(Wq, Wk, Wv, Wo, wqkv);

  // fused QKV projection -> QKVb [8192, 3072]
  gemm_kernel<0><<<dim3(64, 24), 256, 0, stream>>>(xb, wqkv, bq, bk, bv, nullptr, QKVb);

  // scores: P = exp(|Q@K^T|/32) (0 above diag) + per-row partial sums
  gemm_kernel<2><<<dim3(136, BATCH), 256, 0, stream>>>(QKVb, nullptr, nullptr, nullptr, nullptr,
                                                       partial, Sc);

  // deterministic row reciprocal (replaces the softmax pass)
  row_recip<<<32, 256, 0, stream>>>(partial, rowInv);

  // V transpose for NT PV gemm
  transpose_v<<<dim3(DDIM / 64, SDIM / 64, BATCH), 256, 0, stream>>>(QKVb, Vt);

  // O = (P @ V) * rowInv  (causal-truncated K)
  gemm_kernel<3><<<dim3(128, BATCH), 256, 0, stream>>>(Sc, Vt, nullptr, nullptr, nullptr,
                                                       rowInv, Ob);

  // final projection -> fp32 out
  gemm_kernel<1><<<dim3(64, 8), 256, 0, stream>>>(Ob, wo, bo, nullptr, nullptr, nullptr, out);
}

// Round 8
// 207.841 us; speedup vs baseline: 1.1237x; 1.0201x over previous
//
#include <hip/hip_runtime.h>
#include <hip/hip_bf16.h>
#include <cstdint>
#include <math.h>

#define BATCH 4
#define SDIM  2048
#define DDIM  1024
#define QKVN  3072   // fused Q|K|V output width

typedef __attribute__((ext_vector_type(8))) short bf16x8;
typedef __attribute__((ext_vector_type(4))) float f32x4;

__device__ __forceinline__ float bf2f(unsigned short u) {
  union { unsigned int i; float f; } v; v.i = ((unsigned int)u) << 16; return v.f;
}
__device__ __forceinline__ unsigned short f2bf(float f) {
  unsigned int i = __float_as_uint(f);
  return (unsigned short)((i + 0x7FFFu + ((i >> 16) & 1u)) >> 16);  // RNE
}

#define GLOAD16(gp, lp) \
  __builtin_amdgcn_global_load_lds((const __attribute__((address_space(1))) void*)(gp), \
                                   (__attribute__((address_space(3))) void*)(lp), 16, 0, 0)

// ---------------- all fp32 -> bf16 converts in ONE dispatch ----------------
// dest = ws: [ xb 8M | Wq 1M | Wk 1M | Wv 1M | Wo 1M ] shorts (contiguous)
__global__ void cvt_all(const float* __restrict__ x,  const float* __restrict__ wq,
                        const float* __restrict__ wk, const float* __restrict__ wv,
                        const float* __restrict__ wo, unsigned short* __restrict__ out) {
  const int NX = 8 * 1024 * 1024, NW = 1024 * 1024;
  const int total = NX + 4 * NW;
  int i0 = (blockIdx.x * 256 + threadIdx.x) * 4;
  const int stride = gridDim.x * 256 * 4;
  for (int i = i0; i < total; i += stride) {
    const float* src;
    int off;
    if (i < NX)               { src = x;  off = i; }
    else if (i < NX + NW)     { src = wq; off = i - NX; }
    else if (i < NX + 2 * NW) { src = wk; off = i - NX - NW; }
    else if (i < NX + 3 * NW) { src = wv; off = i - NX - 2 * NW; }
    else                      { src = wo; off = i - NX - 3 * NW; }
    float4 v = *reinterpret_cast<const float4*>(src + off);
    ushort4 o;
    o.x = f2bf(v.x); o.y = f2bf(v.y); o.z = f2bf(v.z); o.w = f2bf(v.w);
    *reinterpret_cast<ushort4*>(out + i) = o;
  }
}

// ============ 128x128 tri-buffered MFMA GEMM (proven R3 engine) ==============
// NT: C[m,n] = sum_k A[m,k]*B[n,k]; bf16, K contiguous. Tri-buffer BK=32,
// counted vmcnt(4) (tail drains 0), zero-conflict row-pair XOR swizzle.
// MODE 0: QKV: A=xb[8192,1024] B=Wqkv[3072,1024] C=bf16[8192,3072]+bias(sel)
// MODE 1: out: A=Ob[8192,1024] B=Wo[1024,1024]   C=f32[8192,1024]+bias
// MODE 3: PV:  per-batch, A=P[b][2048,2048], B=Vt[b][1024,2048], K=(ti+1)*128;
//   ti double-remapped for CU load balance; row reciprocal computed in
//   prologue from `aux`=partial sums (fixed-order -> deterministic).
template<int MODE>
__global__ __launch_bounds__(256, 3)
void gemm_kernel(const unsigned short* __restrict__ A,
                 const unsigned short* __restrict__ B,
                 const float* __restrict__ bias0,
                 const float* __restrict__ bias1,
                 const float* __restrict__ bias2,
                 const float* __restrict__ aux,
                 void* __restrict__ C)
{
  __shared__ unsigned short As[3][128 * 32];
  __shared__ unsigned short Bs[3][128 * 32];
  __shared__ float rowinv[128];   // MODE 3 only (512 B)

  const int tid  = threadIdx.x;
  const int wave = tid >> 6;
  const int lane = tid & 63;
  const int wr   = wave >> 1;
  const int wc   = wave & 1;

  const unsigned short *Ab, *Bb;
  int lda, ldb, ktiles;
  int ti, tj, bz = 0;

  if constexpr (MODE == 0 || MODE == 1) {
    ti = blockIdx.x; tj = blockIdx.y;
    Ab = A + (size_t)ti * 128 * DDIM;  lda = DDIM;
    Bb = B + (size_t)tj * 128 * DDIM;  ldb = DDIM;
    ktiles = DDIM / 32;
  } else { // MODE 3
    bz = blockIdx.y;
    const int tr = blockIdx.x >> 3;
    tj = blockIdx.x & 7;
    // load-balance bijection: alternate big/small along x, complement across
    // batch pairs (blocks c and c+256 share a CU under round-robin).
    int base = (tr & 1) ? (15 - (tr >> 1)) : (tr >> 1);
    ti = (bz & 2) ? (15 - base) : base;
    Ab = A + (size_t)bz * SDIM * SDIM + (size_t)ti * 128 * SDIM; lda = SDIM;
    Bb = B + (size_t)bz * DDIM * SDIM + (size_t)tj * 128 * SDIM; ldb = SDIM;
    ktiles = (ti + 1) * 4;

    // row reciprocal from partial sums (slots j < 2*(ti+1), fixed order)
    if (tid < 128) {
      const int gi = ti * 128 + tid;
      const float* p = aux + ((size_t)bz * SDIM + gi) * 32;
      float s = 0.f;
      const int n = 2 * (ti + 1);
      for (int j = 0; j < n; ++j) s += p[j];
      rowinv[tid] = 1.0f / s;      // s >= exp(0) = 1
    }
    __syncthreads();
  }

  f32x4 acc[4][4];
#pragma unroll
  for (int i = 0; i < 4; ++i)
#pragma unroll
    for (int j = 0; j < 4; ++j) acc[i][j] = (f32x4){0.f, 0.f, 0.f, 0.f};

  const int g0   = (lane & 7) ^ (lane >> 3);
  const int rloc = 2 * (lane >> 3) + (g0 >> 2);
  const int colg = (g0 & 3) * 8;

  const int s_  = lane >> 4;
  const int fr  = lane & 15;
  const int p_  = (((fr & 1) << 2) | s_) ^ ((fr >> 1) & 7);
  const int fA  = wr * 2048 + (fr >> 1) * 64 + p_ * 8;
  const int fB  = wc * 2048 + (fr >> 1) * 64 + p_ * 8;

#define STAGE(buf, kt) do {                                                     \
    const size_t kb_ = (size_t)(kt) * 32 + colg;                                \
    GLOAD16(Ab + (size_t)(wave * 16 + rloc) * lda + kb_,      &As[buf][wave * 512]);       \
    GLOAD16(Ab + (size_t)(64 + wave * 16 + rloc) * lda + kb_, &As[buf][(wave + 4) * 512]); \
    GLOAD16(Bb + (size_t)(wave * 16 + rloc) * ldb + kb_,      &Bs[buf][wave * 512]);       \
    GLOAD16(Bb + (size_t)(64 + wave * 16 + rloc) * ldb + kb_, &Bs[buf][(wave + 4) * 512]); \
  } while (0)

  STAGE(0, 0);
  STAGE(1, 1);
  asm volatile("s_waitcnt vmcnt(4)" ::: "memory");
  __builtin_amdgcn_s_barrier();
  __builtin_amdgcn_sched_barrier(0);

  for (int kt = 0; kt < ktiles; ++kt) {
    const int cur = kt % 3;
    const bool st = (kt + 2 < ktiles);
    if (st) STAGE((kt + 2) % 3, kt + 2);

    bf16x8 af[4], bfv[4];
#pragma unroll
    for (int mi = 0; mi < 4; ++mi)
      af[mi] = *reinterpret_cast<const bf16x8*>(&As[cur][fA + mi * 512]);
#pragma unroll
    for (int ni = 0; ni < 4; ++ni)
      bfv[ni] = *reinterpret_cast<const bf16x8*>(&Bs[cur][fB + ni * 512]);

    __builtin_amdgcn_s_setprio(1);
#pragma unroll
    for (int mi = 0; mi < 4; ++mi)
#pragma unroll
      for (int ni = 0; ni < 4; ++ni)
        acc[mi][ni] = __builtin_amdgcn_mfma_f32_16x16x32_bf16(af[mi], bfv[ni], acc[mi][ni], 0, 0, 0);
    __builtin_amdgcn_s_setprio(0);

    if (st) { asm volatile("s_waitcnt vmcnt(4)" ::: "memory"); }
    else    { asm volatile("s_waitcnt vmcnt(0)" ::: "memory"); }
    __builtin_amdgcn_s_barrier();
    __builtin_amdgcn_sched_barrier(0);
  }
#undef STAGE

  // epilogue: C/D layout col = lane&15, row = (lane>>4)*4 + r
  const int row0 = wr * 64, col0 = wc * 64;
  const float* bp = bias0;
  if constexpr (MODE == 0) bp = (tj < 8) ? bias0 : ((tj < 16) ? bias1 : bias2);
#pragma unroll
  for (int mi = 0; mi < 4; ++mi) {
#pragma unroll
    for (int ni = 0; ni < 4; ++ni) {
#pragma unroll
      for (int r = 0; r < 4; ++r) {
        const int lr = row0 + mi * 16 + (lane >> 4) * 4 + r;
        const int lc = col0 + ni * 16 + (lane & 15);
        const float v = acc[mi][ni][r];
        if constexpr (MODE == 0) {
          const int gr = ti * 128 + lr, gc = tj * 128 + lc;
          ((unsigned short*)C)[(size_t)gr * QKVN + gc] = f2bf(v + bp[gc & 1023]);
        } else if constexpr (MODE == 1) {
          const int gr = ti * 128 + lr, gc = tj * 128 + lc;
          ((float*)C)[(size_t)gr * DDIM + gc] = v + bp[gc];
        } else { // MODE 3: normalize by row reciprocal (LDS)
          const int gi = ti * 128 + lr, gd = tj * 128 + lc;
          ((unsigned short*)C)[(size_t)bz * SDIM * DDIM + (size_t)gi * DDIM + gd] = f2bf(v * rowinv[lr]);
        }
      }
    }
  }
}

// ====== scores (tri-buffered engine) + V-transpose merged in one dispatch ====
// grid (136+32, BATCH): x<136 -> triangular score tile: P = exp(|QK^T|/32)
// (0 above diag) + per-row partial sums; x>=136 -> V-transpose slab (16 tiles).
__global__ __launch_bounds__(256, 3)
void attn_prep(const unsigned short* __restrict__ QKVb,
               float* __restrict__ partial,
               unsigned short* __restrict__ Sc,
               unsigned short* __restrict__ Vt)
{
  __shared__ unsigned short sh[24576];   // 48 KB, aliased by both paths

  const int tid  = threadIdx.x;
  const int bz   = blockIdx.y;

  if (blockIdx.x >= 136) {
    // ---- V transpose: one 64-token stripe across all 16 v-dim tiles ----
    unsigned short (*tile)[65] = (unsigned short(*)[65])sh;
    const unsigned short* in = QKVb + (size_t)bz * SDIM * QKVN + 2048;  // V sec
    unsigned short* o = Vt + (size_t)bz * DDIM * SDIM;
    const int tx = tid & 63, ty = tid >> 6;
    const int slab = blockIdx.x - 136;          // 0..31 -> token stripe
    const int r0 = slab * 64;
    for (int t = 0; t < 16; ++t) {
      const int c0 = t * 64;                    // v-dim tile
      for (int r = ty; r < 64; r += 4)
        tile[r][tx] = in[(size_t)(r0 + r) * QKVN + c0 + tx];
      __syncthreads();
      for (int r = ty; r < 64; r += 4)
        o[(size_t)(c0 + r) * SDIM + r0 + tx] = tile[tx][r];
      __syncthreads();
    }
    return;
  }

  // ---- scores path (tri-buffer engine, triangular grid) ----
  unsigned short* AsP = sh;            // 3 x 4096
  unsigned short* BsP = sh + 12288;    // 3 x 4096

  const int wave = tid >> 6;
  const int lane = tid & 63;
  const int wr   = wave >> 1;
  const int wc   = wave & 1;

  int t = blockIdx.x;
  int ti = 0;
  while ((ti + 1) * (ti + 2) / 2 <= t) ++ti;    // triangular decode
  const int tj = t - ti * (ti + 1) / 2;         // tj <= ti
  const unsigned short* Ab = QKVb + (size_t)bz * SDIM * QKVN + (size_t)ti * 128 * QKVN;        // Q
  const unsigned short* Bb = QKVb + (size_t)bz * SDIM * QKVN + (size_t)tj * 128 * QKVN + 1024; // K
  const int ktiles = DDIM / 32;

  f32x4 acc[4][4];
#pragma unroll
  for (int i = 0; i < 4; ++i)
#pragma unroll
    for (int j = 0; j < 4; ++j) acc[i][j] = (f32x4){0.f, 0.f, 0.f, 0.f};

  const int g0   = (lane & 7) ^ (lane >> 3);
  const int rloc = 2 * (lane >> 3) + (g0 >> 2);
  const int colg = (g0 & 3) * 8;

  const int s_  = lane >> 4;
  const int fr  = lane & 15;
  const int p_  = (((fr & 1) << 2) | s_) ^ ((fr >> 1) & 7);
  const int fA  = wr * 2048 + (fr >> 1) * 64 + p_ * 8;
  const int fB  = wc * 2048 + (fr >> 1) * 64 + p_ * 8;

#define STAGE2(buf, kt) do {                                                    \
    const size_t kb_ = (size_t)(kt) * 32 + colg;                                \
    GLOAD16(Ab + (size_t)(wave * 16 + rloc) * QKVN + kb_,      &AsP[(buf) * 4096 + wave * 512]);       \
    GLOAD16(Ab + (size_t)(64 + wave * 16 + rloc) * QKVN + kb_, &AsP[(buf) * 4096 + (wave + 4) * 512]); \
    GLOAD16(Bb + (size_t)(wave * 16 + rloc) * QKVN + kb_,      &BsP[(buf) * 4096 + wave * 512]);       \
    GLOAD16(Bb + (size_t)(64 + wave * 16 + rloc) * QKVN + kb_, &BsP[(buf) * 4096 + (wave + 4) * 512]); \
  } while (0)

  STAGE2(0, 0);
  STAGE2(1, 1);
  asm volatile("s_waitcnt vmcnt(4)" ::: "memory");
  __builtin_amdgcn_s_barrier();
  __builtin_amdgcn_sched_barrier(0);

  for (int kt = 0; kt < ktiles; ++kt) {
    const int cur = kt % 3;
    const bool st = (kt + 2 < ktiles);
    if (st) STAGE2((kt + 2) % 3, kt + 2);

    bf16x8 af[4], bfv[4];
#pragma unroll
    for (int mi = 0; mi < 4; ++mi)
      af[mi] = *reinterpret_cast<const bf16x8*>(&AsP[cur * 4096 + fA + mi * 512]);
#pragma unroll
    for (int ni = 0; ni < 4; ++ni)
      bfv[ni] = *reinterpret_cast<const bf16x8*>(&BsP[cur * 4096 + fB + ni * 512]);

    __builtin_amdgcn_s_setprio(1);
#pragma unroll
    for (int mi = 0; mi < 4; ++mi)
#pragma unroll
      for (int ni = 0; ni < 4; ++ni)
        acc[mi][ni] = __builtin_amdgcn_mfma_f32_16x16x32_bf16(af[mi], bfv[ni], acc[mi][ni], 0, 0, 0);
    __builtin_amdgcn_s_setprio(0);

    if (st) { asm volatile("s_waitcnt vmcnt(4)" ::: "memory"); }
    else    { asm volatile("s_waitcnt vmcnt(0)" ::: "memory"); }
    __builtin_amdgcn_s_barrier();
    __builtin_amdgcn_sched_barrier(0);
  }
#undef STAGE2

  // epilogue: P = exp(|s|/32) (0 above diag), bf16-rounded; per-row partials
  const int row0 = wr * 64, col0 = wc * 64;
#pragma unroll
  for (int mi = 0; mi < 4; ++mi) {
#pragma unroll
    for (int r = 0; r < 4; ++r) {
      const int gi = ti * 128 + row0 + mi * 16 + (lane >> 4) * 4 + r;
      float ps = 0.f;
#pragma unroll
      for (int ni = 0; ni < 4; ++ni) {
        const int gj = tj * 128 + col0 + ni * 16 + (lane & 15);
        float p = (gj > gi) ? 0.f : expf(fabsf(acc[mi][ni][r]) * 0.03125f);
        unsigned short us = f2bf(p);
        Sc[(size_t)bz * SDIM * SDIM + (size_t)gi * SDIM + gj] = us;
        ps += bf2f(us);
      }
      ps += __shfl_xor(ps, 1);
      ps += __shfl_xor(ps, 2);
      ps += __shfl_xor(ps, 4);
      ps += __shfl_xor(ps, 8);
      if ((lane & 15) == 0)
        partial[((size_t)bz * SDIM + gi) * 32 + tj * 2 + wc] = ps;
    }
  }
}

// ---------------- host launch ----------------
extern "C" void kernel_launch(void* const* d_in, const int* in_sizes, int n_in,
                              void* d_out, int out_size, void* d_ws, size_t ws_size,
                              hipStream_t stream) {
  const float* x  = (const float*)d_in[0];
  const float* Wq = (const float*)d_in[1];
  const float* bq = (const float*)d_in[2];
  const float* Wk = (const float*)d_in[3];
  const float* bk = (const float*)d_in[4];
  const float* Wv = (const float*)d_in[5];
  const float* bv = (const float*)d_in[6];
  const float* Wo = (const float*)d_in[7];
  const float* bo = (const float*)d_in[8];
  float* out = (float*)d_out;

  const size_t NTOK = (size_t)BATCH * SDIM;       // 8192
  unsigned short* ws = (unsigned short*)d_ws;
  unsigned short* xb   = ws;                          // [8192,1024]
  unsigned short* wqkv = xb + NTOK * DDIM;            // [3072,1024]
  unsigned short* wo   = wqkv + (size_t)QKVN * DDIM;  // [1024,1024]
  unsigned short* QKVb = wo + (size_t)DDIM * DDIM;    // [8192,3072]
  unsigned short* Vt   = QKVb + NTOK * QKVN;          // [B,1024,2048]
  unsigned short* Ob   = Vt + NTOK * DDIM;            // [8192,1024]
  unsigned short* Sc   = Ob + NTOK * DDIM;            // [B,2048,2048] = P (exp)
  float* partial = (float*)(Sc + (size_t)BATCH * SDIM * SDIM);  // [8192][32]

  // all converts in one dispatch (dest regions contiguous from ws)
  cvt_all<<<2048, 256, 0, stream>>>(x, Wq, Wk, Wv, Wo, xb);

  // fused QKV projection -> QKVb [8192, 3072]
  gemm_kernel<0><<<dim3(64, 24), 256, 0, stream>>>(xb, wqkv, bq, bk, bv, nullptr, QKVb);

  // scores (P=exp, partial sums) + V-transpose, one dispatch
  attn_prep<<<dim3(136 + 32, BATCH), 256, 0, stream>>>(QKVb, partial, Sc, Vt);

  // O = (P @ V) * rowInv  (causal-truncated K; balanced ti remap; recip in prologue)
  gemm_kernel<3><<<dim3(128, BATCH), 256, 0, stream>>>(Sc, Vt, nullptr, nullptr, nullptr,
                                                       partial, Ob);

  // final projection -> fp32 out
  gemm_kernel<1><<<dim3(64, 8), 256, 0, stream>>>(Ob, wo, bo, nullptr, nullptr, nullptr, out);
}

// Round 9
// 186.446 us; speedup vs baseline: 1.2527x; 1.1147x over previous
//
#include <hip/hip_runtime.h>
#include <hip/hip_bf16.h>
#include <cstdint>
#include <math.h>

#define BATCH 4
#define SDIM  2048
#define DDIM  1024
#define QKVN  3072   // fused Q|K|V output width

typedef __attribute__((ext_vector_type(8))) short bf16x8;
typedef __attribute__((ext_vector_type(4))) float f32x4;

__device__ __forceinline__ float bf2f(unsigned short u) {
  union { unsigned int i; float f; } v; v.i = ((unsigned int)u) << 16; return v.f;
}
__device__ __forceinline__ unsigned short f2bf(float f) {
  unsigned int i = __float_as_uint(f);
  return (unsigned short)((i + 0x7FFFu + ((i >> 16) & 1u)) >> 16);  // RNE
}

#define GLOAD16(gp, lp) \
  __builtin_amdgcn_global_load_lds((const __attribute__((address_space(1))) void*)(gp), \
                                   (__attribute__((address_space(3))) void*)(lp), 16, 0, 0)

// ---------------- all fp32 -> bf16 converts in ONE dispatch ----------------
// dest = ws: [ xb 8M | Wq 1M | Wk 1M | Wv 1M | Wo 1M ] shorts (contiguous)
__global__ void cvt_all(const float* __restrict__ x,  const float* __restrict__ wq,
                        const float* __restrict__ wk, const float* __restrict__ wv,
                        const float* __restrict__ wo, unsigned short* __restrict__ out) {
  const int NX = 8 * 1024 * 1024, NW = 1024 * 1024;
  const int total = NX + 4 * NW;
  int i0 = (blockIdx.x * 256 + threadIdx.x) * 4;
  const int stride = gridDim.x * 256 * 4;
  for (int i = i0; i < total; i += stride) {
    const float* src;
    int off;
    if (i < NX)               { src = x;  off = i; }
    else if (i < NX + NW)     { src = wq; off = i - NX; }
    else if (i < NX + 2 * NW) { src = wk; off = i - NX - NW; }
    else if (i < NX + 3 * NW) { src = wv; off = i - NX - 2 * NW; }
    else                      { src = wo; off = i - NX - 3 * NW; }
    float4 v = *reinterpret_cast<const float4*>(src + off);
    ushort4 o;
    o.x = f2bf(v.x); o.y = f2bf(v.y); o.z = f2bf(v.z); o.w = f2bf(v.w);
    *reinterpret_cast<ushort4*>(out + i) = o;
  }
}

// ============ 128x128 tri-buffered MFMA GEMM (proven R3 engine) ==============
// NT: C[m,n] = sum_k A[m,k]*B[n,k]; bf16, K contiguous. Tri-buffer BK=32,
// counted vmcnt(4) (tail drains 0), zero-conflict row-pair XOR swizzle.
// MODE 0: QKV: A=xb[8192,1024] B=Wqkv[3072,1024] C=bf16[8192,3072]+bias(sel)
// MODE 1: PV+out: per-batch, A=P[b][2048,2048] B=VWo_t[b][1024,2048],
//   K=(ti+1)*128 (causal-truncated), ti double-remapped for CU balance;
//   rowinv from aux partials in prologue; C = fp32 out = v*rowinv + bo.
template<int MODE>
__global__ __launch_bounds__(256, 3)
void gemm_kernel(const unsigned short* __restrict__ A,
                 const unsigned short* __restrict__ B,
                 const float* __restrict__ bias0,
                 const float* __restrict__ bias1,
                 const float* __restrict__ bias2,
                 const float* __restrict__ aux,
                 void* __restrict__ C)
{
  __shared__ unsigned short As[3][128 * 32];
  __shared__ unsigned short Bs[3][128 * 32];
  __shared__ float rowinv[128];   // MODE 1 only

  const int tid  = threadIdx.x;
  const int wave = tid >> 6;
  const int lane = tid & 63;
  const int wr   = wave >> 1;
  const int wc   = wave & 1;

  const unsigned short *Ab, *Bb;
  int lda, ldb, ktiles;
  int ti, tj, bz = 0;

  if constexpr (MODE == 0) {
    ti = blockIdx.x; tj = blockIdx.y;
    Ab = A + (size_t)ti * 128 * DDIM;  lda = DDIM;
    Bb = B + (size_t)tj * 128 * DDIM;  ldb = DDIM;
    ktiles = DDIM / 32;
  } else { // MODE 1: PV + output write
    bz = blockIdx.y;
    const int tr = blockIdx.x >> 3;
    tj = blockIdx.x & 7;
    // load-balance bijection: alternate big/small along x, complement across
    // batch pairs (blocks c and c+256 share a CU under round-robin).
    int base = (tr & 1) ? (15 - (tr >> 1)) : (tr >> 1);
    ti = (bz & 2) ? (15 - base) : base;
    Ab = A + (size_t)bz * SDIM * SDIM + (size_t)ti * 128 * SDIM; lda = SDIM;
    Bb = B + (size_t)bz * DDIM * SDIM + (size_t)tj * 128 * SDIM; ldb = SDIM;
    ktiles = (ti + 1) * 4;

    // row reciprocal from partial sums (slots j < 2*(ti+1), fixed order)
    if (tid < 128) {
      const int gi = ti * 128 + tid;
      const float* p = aux + ((size_t)bz * SDIM + gi) * 32;
      float s = 0.f;
      const int n = 2 * (ti + 1);
      for (int j = 0; j < n; ++j) s += p[j];
      rowinv[tid] = 1.0f / s;      // s >= exp(0) = 1
    }
    __syncthreads();
  }

  f32x4 acc[4][4];
#pragma unroll
  for (int i = 0; i < 4; ++i)
#pragma unroll
    for (int j = 0; j < 4; ++j) acc[i][j] = (f32x4){0.f, 0.f, 0.f, 0.f};

  const int g0   = (lane & 7) ^ (lane >> 3);
  const int rloc = 2 * (lane >> 3) + (g0 >> 2);
  const int colg = (g0 & 3) * 8;

  const int s_  = lane >> 4;
  const int fr  = lane & 15;
  const int p_  = (((fr & 1) << 2) | s_) ^ ((fr >> 1) & 7);
  const int fA  = wr * 2048 + (fr >> 1) * 64 + p_ * 8;
  const int fB  = wc * 2048 + (fr >> 1) * 64 + p_ * 8;

#define STAGE(buf, kt) do {                                                     \
    const size_t kb_ = (size_t)(kt) * 32 + colg;                                \
    GLOAD16(Ab + (size_t)(wave * 16 + rloc) * lda + kb_,      &As[buf][wave * 512]);       \
    GLOAD16(Ab + (size_t)(64 + wave * 16 + rloc) * lda + kb_, &As[buf][(wave + 4) * 512]); \
    GLOAD16(Bb + (size_t)(wave * 16 + rloc) * ldb + kb_,      &Bs[buf][wave * 512]);       \
    GLOAD16(Bb + (size_t)(64 + wave * 16 + rloc) * ldb + kb_, &Bs[buf][(wave + 4) * 512]); \
  } while (0)

  STAGE(0, 0);
  STAGE(1, 1);
  asm volatile("s_waitcnt vmcnt(4)" ::: "memory");
  __builtin_amdgcn_s_barrier();
  __builtin_amdgcn_sched_barrier(0);

  for (int kt = 0; kt < ktiles; ++kt) {
    const int cur = kt % 3;
    const bool st = (kt + 2 < ktiles);
    if (st) STAGE((kt + 2) % 3, kt + 2);

    bf16x8 af[4], bfv[4];
#pragma unroll
    for (int mi = 0; mi < 4; ++mi)
      af[mi] = *reinterpret_cast<const bf16x8*>(&As[cur][fA + mi * 512]);
#pragma unroll
    for (int ni = 0; ni < 4; ++ni)
      bfv[ni] = *reinterpret_cast<const bf16x8*>(&Bs[cur][fB + ni * 512]);

    __builtin_amdgcn_s_setprio(1);
#pragma unroll
    for (int mi = 0; mi < 4; ++mi)
#pragma unroll
      for (int ni = 0; ni < 4; ++ni)
        acc[mi][ni] = __builtin_amdgcn_mfma_f32_16x16x32_bf16(af[mi], bfv[ni], acc[mi][ni], 0, 0, 0);
    __builtin_amdgcn_s_setprio(0);

    if (st) { asm volatile("s_waitcnt vmcnt(4)" ::: "memory"); }
    else    { asm volatile("s_waitcnt vmcnt(0)" ::: "memory"); }
    __builtin_amdgcn_s_barrier();
    __builtin_amdgcn_sched_barrier(0);
  }
#undef STAGE

  // epilogue: C/D layout col = lane&15, row = (lane>>4)*4 + r
  const int row0 = wr * 64, col0 = wc * 64;
  const float* bp = bias0;
  if constexpr (MODE == 0) bp = (tj < 8) ? bias0 : ((tj < 16) ? bias1 : bias2);
#pragma unroll
  for (int mi = 0; mi < 4; ++mi) {
#pragma unroll
    for (int ni = 0; ni < 4; ++ni) {
#pragma unroll
      for (int r = 0; r < 4; ++r) {
        const int lr = row0 + mi * 16 + (lane >> 4) * 4 + r;
        const int lc = col0 + ni * 16 + (lane & 15);
        const float v = acc[mi][ni][r];
        if constexpr (MODE == 0) {
          const int gr = ti * 128 + lr, gc = tj * 128 + lc;
          ((unsigned short*)C)[(size_t)gr * QKVN + gc] = f2bf(v + bp[gc & 1023]);
        } else { // MODE 1: final output, fp32, normalized + bias
          const int gi = ti * 128 + lr, gd = tj * 128 + lc;
          ((float*)C)[((size_t)bz * SDIM + gi) * DDIM + gd] = v * rowinv[lr] + bias0[gd];
        }
      }
    }
  }
}

// ====== scores + VWo^T merged in one dispatch (both tri-buffered engine) =====
// grid (136+128, BATCH):
//   x <  136: triangular score tile: P = exp(|QK^T|/32) (0 above diag) +
//             per-row partial sums -> partial[row*32 + tj*2 + wc]
//   x >= 136: VWo^T tile: VWo_t[b][d,s] = sum_v Wo[d,v] * V[b][s,v]
//             (A = Wo [1024,1024], B = V section of QKVb, ld QKVN)
__global__ __launch_bounds__(256, 3)
void attn_prep(const unsigned short* __restrict__ QKVb,
               const unsigned short* __restrict__ wo,
               float* __restrict__ partial,
               unsigned short* __restrict__ Sc,
               unsigned short* __restrict__ VWo_t)
{
  __shared__ unsigned short As[3][128 * 32];
  __shared__ unsigned short Bs[3][128 * 32];

  const int tid  = threadIdx.x;
  const int bz   = blockIdx.y;
  const int wave = tid >> 6;
  const int lane = tid & 63;
  const int wr   = wave >> 1;
  const int wc   = wave & 1;

  const bool is_score = (blockIdx.x < 136);
  const unsigned short *Ab, *Bb;
  int lda, ldb, ti, tj;

  if (is_score) {
    int t = blockIdx.x;
    ti = 0;
    while ((ti + 1) * (ti + 2) / 2 <= t) ++ti;   // triangular decode
    tj = t - ti * (ti + 1) / 2;                  // tj <= ti
    Ab = QKVb + (size_t)bz * SDIM * QKVN + (size_t)ti * 128 * QKVN;        lda = QKVN; // Q
    Bb = QKVb + (size_t)bz * SDIM * QKVN + (size_t)tj * 128 * QKVN + 1024; ldb = QKVN; // K
  } else {
    const int tv = blockIdx.x - 136;             // 0..127
    ti = tv >> 4;                                // Wo row tile (d), 0..7
    tj = tv & 15;                                // V row tile (s), 0..15
    Ab = wo + (size_t)ti * 128 * DDIM;                                     lda = DDIM;
    Bb = QKVb + (size_t)bz * SDIM * QKVN + (size_t)tj * 128 * QKVN + 2048; ldb = QKVN; // V
  }
  const int ktiles = DDIM / 32;

  f32x4 acc[4][4];
#pragma unroll
  for (int i = 0; i < 4; ++i)
#pragma unroll
    for (int j = 0; j < 4; ++j) acc[i][j] = (f32x4){0.f, 0.f, 0.f, 0.f};

  const int g0   = (lane & 7) ^ (lane >> 3);
  const int rloc = 2 * (lane >> 3) + (g0 >> 2);
  const int colg = (g0 & 3) * 8;

  const int s_  = lane >> 4;
  const int fr  = lane & 15;
  const int p_  = (((fr & 1) << 2) | s_) ^ ((fr >> 1) & 7);
  const int fA  = wr * 2048 + (fr >> 1) * 64 + p_ * 8;
  const int fB  = wc * 2048 + (fr >> 1) * 64 + p_ * 8;

#define STAGE2(buf, kt) do {                                                    \
    const size_t kb_ = (size_t)(kt) * 32 + colg;                                \
    GLOAD16(Ab + (size_t)(wave * 16 + rloc) * lda + kb_,      &As[buf][wave * 512]);       \
    GLOAD16(Ab + (size_t)(64 + wave * 16 + rloc) * lda + kb_, &As[buf][(wave + 4) * 512]); \
    GLOAD16(Bb + (size_t)(wave * 16 + rloc) * ldb + kb_,      &Bs[buf][wave * 512]);       \
    GLOAD16(Bb + (size_t)(64 + wave * 16 + rloc) * ldb + kb_, &Bs[buf][(wave + 4) * 512]); \
  } while (0)

  STAGE2(0, 0);
  STAGE2(1, 1);
  asm volatile("s_waitcnt vmcnt(4)" ::: "memory");
  __builtin_amdgcn_s_barrier();
  __builtin_amdgcn_sched_barrier(0);

  for (int kt = 0; kt < ktiles; ++kt) {
    const int cur = kt % 3;
    const bool st = (kt + 2 < ktiles);
    if (st) STAGE2((kt + 2) % 3, kt + 2);

    bf16x8 af[4], bfv[4];
#pragma unroll
    for (int mi = 0; mi < 4; ++mi)
      af[mi] = *reinterpret_cast<const bf16x8*>(&As[cur][fA + mi * 512]);
#pragma unroll
    for (int ni = 0; ni < 4; ++ni)
      bfv[ni] = *reinterpret_cast<const bf16x8*>(&Bs[cur][fB + ni * 512]);

    __builtin_amdgcn_s_setprio(1);
#pragma unroll
    for (int mi = 0; mi < 4; ++mi)
#pragma unroll
      for (int ni = 0; ni < 4; ++ni)
        acc[mi][ni] = __builtin_amdgcn_mfma_f32_16x16x32_bf16(af[mi], bfv[ni], acc[mi][ni], 0, 0, 0);
    __builtin_amdgcn_s_setprio(0);

    if (st) { asm volatile("s_waitcnt vmcnt(4)" ::: "memory"); }
    else    { asm volatile("s_waitcnt vmcnt(0)" ::: "memory"); }
    __builtin_amdgcn_s_barrier();
    __builtin_amdgcn_sched_barrier(0);
  }
#undef STAGE2

  const int row0 = wr * 64, col0 = wc * 64;
  if (is_score) {
    // P = exp(|s|/32) (0 above diag), bf16-rounded; per-row partial sums
#pragma unroll
    for (int mi = 0; mi < 4; ++mi) {
#pragma unroll
      for (int r = 0; r < 4; ++r) {
        const int gi = ti * 128 + row0 + mi * 16 + (lane >> 4) * 4 + r;
        float ps = 0.f;
#pragma unroll
        for (int ni = 0; ni < 4; ++ni) {
          const int gj = tj * 128 + col0 + ni * 16 + (lane & 15);
          float p = (gj > gi) ? 0.f : __expf(fabsf(acc[mi][ni][r]) * 0.03125f);
          unsigned short us = f2bf(p);
          Sc[(size_t)bz * SDIM * SDIM + (size_t)gi * SDIM + gj] = us;
          ps += bf2f(us);
        }
        ps += __shfl_xor(ps, 1);
        ps += __shfl_xor(ps, 2);
        ps += __shfl_xor(ps, 4);
        ps += __shfl_xor(ps, 8);
        if ((lane & 15) == 0)
          partial[((size_t)bz * SDIM + gi) * 32 + tj * 2 + wc] = ps;
      }
    }
  } else {
    // VWo^T tile: [d, s] row-major, ld = SDIM
#pragma unroll
    for (int mi = 0; mi < 4; ++mi) {
#pragma unroll
      for (int ni = 0; ni < 4; ++ni) {
#pragma unroll
        for (int r = 0; r < 4; ++r) {
          const int gd = ti * 128 + row0 + mi * 16 + (lane >> 4) * 4 + r;
          const int gs = tj * 128 + col0 + ni * 16 + (lane & 15);
          VWo_t[(size_t)bz * DDIM * SDIM + (size_t)gd * SDIM + gs] = f2bf(acc[mi][ni][r]);
        }
      }
    }
  }
}

// ---------------- host launch ----------------
extern "C" void kernel_launch(void* const* d_in, const int* in_sizes, int n_in,
                              void* d_out, int out_size, void* d_ws, size_t ws_size,
                              hipStream_t stream) {
  const float* x  = (const float*)d_in[0];
  const float* Wq = (const float*)d_in[1];
  const float* bq = (const float*)d_in[2];
  const float* Wk = (const float*)d_in[3];
  const float* bk = (const float*)d_in[4];
  const float* Wv = (const float*)d_in[5];
  const float* bv = (const float*)d_in[6];
  const float* Wo = (const float*)d_in[7];
  const float* bo = (const float*)d_in[8];
  float* out = (float*)d_out;

  const size_t NTOK = (size_t)BATCH * SDIM;       // 8192
  unsigned short* ws = (unsigned short*)d_ws;
  unsigned short* xb   = ws;                          // [8192,1024]
  unsigned short* wqkv = xb + NTOK * DDIM;            // [3072,1024]
  unsigned short* wo   = wqkv + (size_t)QKVN * DDIM;  // [1024,1024]
  unsigned short* QKVb = wo + (size_t)DDIM * DDIM;    // [8192,3072]
  unsigned short* VWot = QKVb + NTOK * QKVN;          // [B,1024,2048] = (V@Wo^T)^T
  unsigned short* Sc   = VWot + NTOK * DDIM;          // [B,2048,2048] = P (exp)
  float* partial = (float*)(Sc + (size_t)BATCH * SDIM * SDIM);  // [8192][32]

  // all converts in one dispatch (dest regions contiguous from ws)
  cvt_all<<<2048, 256, 0, stream>>>(x, Wq, Wk, Wv, Wo, xb);

  // fused QKV projection -> QKVb [8192, 3072]
  gemm_kernel<0><<<dim3(64, 24), 256, 0, stream>>>(xb, wqkv, bq, bk, bv, nullptr, QKVb);

  // scores (P=exp, partial sums)  ||  VWo^T  (one dispatch, independent halves)
  attn_prep<<<dim3(136 + 128, BATCH), 256, 0, stream>>>(QKVb, wo, partial, Sc, VWot);

  // out = rowInv * (P @ VWo^T) + bo   (causal-truncated K; balanced ti remap)
  gemm_kernel<1><<<dim3(128, BATCH), 256, 0, stream>>>(Sc, VWot, bo, nullptr, nullptr,
                                                       partial, out);
}

// Round 11
// 175.577 us; speedup vs baseline: 1.3302x; 1.0619x over previous
//
#include <hip/hip_runtime.h>
#include <hip/hip_bf16.h>
#include <cstdint>
#include <math.h>

#define BATCH 4
#define SDIM  2048
#define DDIM  1024
#define QKVN  3072   // fused Q|K|V output width

typedef __attribute__((ext_vector_type(8))) short bf16x8;
typedef __attribute__((ext_vector_type(4))) float f32x4;

__device__ __forceinline__ float bf2f(unsigned short u) {
  union { unsigned int i; float f; } v; v.i = ((unsigned int)u) << 16; return v.f;
}
__device__ __forceinline__ unsigned short f2bf(float f) {
  unsigned int i = __float_as_uint(f);
  return (unsigned short)((i + 0x7FFFu + ((i >> 16) & 1u)) >> 16);  // RNE
}

#define GLOAD16(gp, lp) \
  __builtin_amdgcn_global_load_lds((const __attribute__((address_space(1))) void*)(gp), \
                                   (__attribute__((address_space(3))) void*)(lp), 16, 0, 0)

// ---------------- all fp32 -> bf16 converts in ONE dispatch ----------------
// dest = ws: [ xb 8M | Wq 1M | Wk 1M | Wv 1M | Wo 1M ] shorts (contiguous)
__global__ void cvt_all(const float* __restrict__ x,  const float* __restrict__ wq,
                        const float* __restrict__ wk, const float* __restrict__ wv,
                        const float* __restrict__ wo, unsigned short* __restrict__ out) {
  const int NX = 8 * 1024 * 1024, NW = 1024 * 1024;
  const int total = NX + 4 * NW;
  int i0 = (blockIdx.x * 256 + threadIdx.x) * 4;
  const int stride = gridDim.x * 256 * 4;
  for (int i = i0; i < total; i += stride) {
    const float* src;
    int off;
    if (i < NX)               { src = x;  off = i; }
    else if (i < NX + NW)     { src = wq; off = i - NX; }
    else if (i < NX + 2 * NW) { src = wk; off = i - NX - NW; }
    else if (i < NX + 3 * NW) { src = wv; off = i - NX - 2 * NW; }
    else                      { src = wo; off = i - NX - 3 * NW; }
    float4 v = *reinterpret_cast<const float4*>(src + off);
    ushort4 o;
    o.x = f2bf(v.x); o.y = f2bf(v.y); o.z = f2bf(v.z); o.w = f2bf(v.w);
    *reinterpret_cast<ushort4*>(out + i) = o;
  }
}

// ============ 128x128 tri-buffered MFMA GEMM (proven R3 engine) ==============
// NT: C[m,n] = sum_k A[m,k]*B[n,k]; bf16, K contiguous. Tri-buffer BK=32,
// counted vmcnt(4) (tail drains 0), zero-conflict row-pair XOR swizzle.
// Grids are 1D with XCD-locality decode (xcd = blockIdx.x & 7 owns a
// contiguous work band -> per-XCD L2 working set fits ~4MB).
// MODE 0: QKV: A=xb[8192,1024] B=Wqkv[3072,1024] C=bf16[8192,3072]+bias(sel)
//   decode: xcd owns ti band of 8; same-XCD consecutive blocks share B tile.
// MODE 1: PV+out: per-batch, A=P[b][2048,2048] B=VWo_t[b][1024,2048],
//   K=(ti+1)*128; xcd owns one batch-half of tj;
//   ti = (tr<8)? tr : 23-tr  -- bijective (enumerated), CU-pair (f,f+256)
//   gives ti'=15-ti so per-CU work is constant 17 K-tiles;
//   rowinv from aux partials in prologue; C = fp32 out = v*rowinv + bo.
template<int MODE>
__global__ __launch_bounds__(256, 3)
void gemm_kernel(const unsigned short* __restrict__ A,
                 const unsigned short* __restrict__ B,
                 const float* __restrict__ bias0,
                 const float* __restrict__ bias1,
                 const float* __restrict__ bias2,
                 const float* __restrict__ aux,
                 void* __restrict__ C)
{
  __shared__ unsigned short As[3][128 * 32];
  __shared__ unsigned short Bs[3][128 * 32];
  __shared__ float rowinv[128];   // MODE 1 only

  const int tid  = threadIdx.x;
  const int wave = tid >> 6;
  const int lane = tid & 63;
  const int wr   = wave >> 1;
  const int wc   = wave & 1;

  const unsigned short *Ab, *Bb;
  int lda, ldb, ktiles;
  int ti, tj, bz = 0;

  if constexpr (MODE == 0) {
    // 1536 blocks: xcd = f&7 owns ti in [xcd*8, xcd*8+8); tj outer (B reuse)
    const int f = blockIdx.x;
    const int xcd = f & 7, s = f >> 3;        // s: 0..191
    ti = xcd * 8 + (s & 7);                   // 0..63
    tj = s >> 3;                              // 0..23
    Ab = A + (size_t)ti * 128 * DDIM;  lda = DDIM;
    Bb = B + (size_t)tj * 128 * DDIM;  ldb = DDIM;
    ktiles = DDIM / 32;
  } else { // MODE 1: PV + output write, 512 blocks 1D
    const int f = blockIdx.x;
    const int xcd = f & 7, idx = f >> 3;      // idx: 0..63
    bz = xcd >> 1;
    tj = (xcd & 1) * 4 + (idx & 3);           // 0..7
    const int tr = idx >> 2;                  // 0..15
    // bijective + CU-pair balanced: tr<8 -> ti=tr; tr>=8 -> ti=23-tr (15..8)
    ti = (tr < 8) ? tr : (23 - tr);
    Ab = A + (size_t)bz * SDIM * SDIM + (size_t)ti * 128 * SDIM; lda = SDIM;
    Bb = B + (size_t)bz * DDIM * SDIM + (size_t)tj * 128 * SDIM; ldb = SDIM;
    ktiles = (ti + 1) * 4;

    // row reciprocal from partial sums (slots j < 2*(ti+1), fixed order)
    if (tid < 128) {
      const int gi = ti * 128 + tid;
      const float* p = aux + ((size_t)bz * SDIM + gi) * 32;
      float s = 0.f;
      const int n = 2 * (ti + 1);
      for (int j = 0; j < n; ++j) s += p[j];
      rowinv[tid] = 1.0f / s;      // s >= exp(0) = 1
    }
    __syncthreads();
  }

  f32x4 acc[4][4];
#pragma unroll
  for (int i = 0; i < 4; ++i)
#pragma unroll
    for (int j = 0; j < 4; ++j) acc[i][j] = (f32x4){0.f, 0.f, 0.f, 0.f};

  const int g0   = (lane & 7) ^ (lane >> 3);
  const int rloc = 2 * (lane >> 3) + (g0 >> 2);
  const int colg = (g0 & 3) * 8;

  const int s_  = lane >> 4;
  const int fr  = lane & 15;
  const int p_  = (((fr & 1) << 2) | s_) ^ ((fr >> 1) & 7);
  const int fA  = wr * 2048 + (fr >> 1) * 64 + p_ * 8;
  const int fB  = wc * 2048 + (fr >> 1) * 64 + p_ * 8;

#define STAGE(buf, kt) do {                                                     \
    const size_t kb_ = (size_t)(kt) * 32 + colg;                                \
    GLOAD16(Ab + (size_t)(wave * 16 + rloc) * lda + kb_,      &As[buf][wave * 512]);       \
    GLOAD16(Ab + (size_t)(64 + wave * 16 + rloc) * lda + kb_, &As[buf][(wave + 4) * 512]); \
    GLOAD16(Bb + (size_t)(wave * 16 + rloc) * ldb + kb_,      &Bs[buf][wave * 512]);       \
    GLOAD16(Bb + (size_t)(64 + wave * 16 + rloc) * ldb + kb_, &Bs[buf][(wave + 4) * 512]); \
  } while (0)

  STAGE(0, 0);
  STAGE(1, 1);
  asm volatile("s_waitcnt vmcnt(4)" ::: "memory");
  __builtin_amdgcn_s_barrier();
  __builtin_amdgcn_sched_barrier(0);

  for (int kt = 0; kt < ktiles; ++kt) {
    const int cur = kt % 3;
    const bool st = (kt + 2 < ktiles);
    if (st) STAGE((kt + 2) % 3, kt + 2);

    bf16x8 af[4], bfv[4];
#pragma unroll
    for (int mi = 0; mi < 4; ++mi)
      af[mi] = *reinterpret_cast<const bf16x8*>(&As[cur][fA + mi * 512]);
#pragma unroll
    for (int ni = 0; ni < 4; ++ni)
      bfv[ni] = *reinterpret_cast<const bf16x8*>(&Bs[cur][fB + ni * 512]);

    __builtin_amdgcn_s_setprio(1);
#pragma unroll
    for (int mi = 0; mi < 4; ++mi)
#pragma unroll
      for (int ni = 0; ni < 4; ++ni)
        acc[mi][ni] = __builtin_amdgcn_mfma_f32_16x16x32_bf16(af[mi], bfv[ni], acc[mi][ni], 0, 0, 0);
    __builtin_amdgcn_s_setprio(0);

    if (st) { asm volatile("s_waitcnt vmcnt(4)" ::: "memory"); }
    else    { asm volatile("s_waitcnt vmcnt(0)" ::: "memory"); }
    __builtin_amdgcn_s_barrier();
    __builtin_amdgcn_sched_barrier(0);
  }
#undef STAGE

  // epilogue: C/D layout col = lane&15, row = (lane>>4)*4 + r
  const int row0 = wr * 64, col0 = wc * 64;
  const float* bp = bias0;
  if constexpr (MODE == 0) bp = (tj < 8) ? bias0 : ((tj < 16) ? bias1 : bias2);
#pragma unroll
  for (int mi = 0; mi < 4; ++mi) {
#pragma unroll
    for (int ni = 0; ni < 4; ++ni) {
#pragma unroll
      for (int r = 0; r < 4; ++r) {
        const int lr = row0 + mi * 16 + (lane >> 4) * 4 + r;
        const int lc = col0 + ni * 16 + (lane & 15);
        const float v = acc[mi][ni][r];
        if constexpr (MODE == 0) {
          const int gr = ti * 128 + lr, gc = tj * 128 + lc;
          ((unsigned short*)C)[(size_t)gr * QKVN + gc] = f2bf(v + bp[gc & 1023]);
        } else { // MODE 1: final output, fp32, normalized + bias
          const int gi = ti * 128 + lr, gd = tj * 128 + lc;
          ((float*)C)[((size_t)bz * SDIM + gi) * DDIM + gd] = v * rowinv[lr] + bias0[gd];
        }
      }
    }
  }
}

// ====== scores + VWo^T merged in one dispatch (both tri-buffered engine) =====
// 1D grid 1056 with XCD-locality decode (xcd = flat & 7):
//   flat <  544: scores — xcd owns one batch-half (68 triangular tiles):
//     P = exp(|QK^T|/32) (0 above diag) + per-row partials
//   flat >= 544: VWo^T — xcd owns one batch-half (Wo band x 8 V tiles):
//     VWo_t[b][d,s] = sum_v Wo[d,v] * V[b][s,v]
__global__ __launch_bounds__(256, 3)
void attn_prep(const unsigned short* __restrict__ QKVb,
               const unsigned short* __restrict__ wo,
               float* __restrict__ partial,
               unsigned short* __restrict__ Sc,
               unsigned short* __restrict__ VWo_t)
{
  __shared__ unsigned short As[3][128 * 32];
  __shared__ unsigned short Bs[3][128 * 32];

  const int tid  = threadIdx.x;
  const int wave = tid >> 6;
  const int lane = tid & 63;
  const int wr   = wave >> 1;
  const int wc   = wave & 1;

  const int flat = blockIdx.x;
  const bool is_score = (flat < 544);
  const unsigned short *Ab, *Bb;
  int lda, ldb, ti, tj, bz;

  if (is_score) {
    const int xcd = flat & 7, idx = flat >> 3;      // idx: 0..67
    bz = xcd >> 1;
    int t = (xcd & 1) * 68 + idx;                   // 0..135
    ti = 0;
    while ((ti + 1) * (ti + 2) / 2 <= t) ++ti;      // triangular decode
    tj = t - ti * (ti + 1) / 2;                     // tj <= ti
    Ab = QKVb + (size_t)bz * SDIM * QKVN + (size_t)ti * 128 * QKVN;        lda = QKVN; // Q
    Bb = QKVb + (size_t)bz * SDIM * QKVN + (size_t)tj * 128 * QKVN + 1024; ldb = QKVN; // K
  } else {
    const int v = flat - 544;
    const int xcd = v & 7, idx = v >> 3;            // idx: 0..63
    bz = xcd >> 1;
    ti = idx >> 3;                                  // Wo row tile (d), 0..7
    tj = (xcd & 1) * 8 + (idx & 7);                 // V row tile (s), 0..15
    Ab = wo + (size_t)ti * 128 * DDIM;                                     lda = DDIM;
    Bb = QKVb + (size_t)bz * SDIM * QKVN + (size_t)tj * 128 * QKVN + 2048; ldb = QKVN; // V
  }
  const int ktiles = DDIM / 32;

  f32x4 acc[4][4];
#pragma unroll
  for (int i = 0; i < 4; ++i)
#pragma unroll
    for (int j = 0; j < 4; ++j) acc[i][j] = (f32x4){0.f, 0.f, 0.f, 0.f};

  const int g0   = (lane & 7) ^ (lane >> 3);
  const int rloc = 2 * (lane >> 3) + (g0 >> 2);
  const int colg = (g0 & 3) * 8;

  const int s_  = lane >> 4;
  const int fr  = lane & 15;
  const int p_  = (((fr & 1) << 2) | s_) ^ ((fr >> 1) & 7);
  const int fA  = wr * 2048 + (fr >> 1) * 64 + p_ * 8;
  const int fB  = wc * 2048 + (fr >> 1) * 64 + p_ * 8;

#define STAGE2(buf, kt) do {                                                    \
    const size_t kb_ = (size_t)(kt) * 32 + colg;                                \
    GLOAD16(Ab + (size_t)(wave * 16 + rloc) * lda + kb_,      &As[buf][wave * 512]);       \
    GLOAD16(Ab + (size_t)(64 + wave * 16 + rloc) * lda + kb_, &As[buf][(wave + 4) * 512]); \
    GLOAD16(Bb + (size_t)(wave * 16 + rloc) * ldb + kb_,      &Bs[buf][wave * 512]);       \
    GLOAD16(Bb + (size_t)(64 + wave * 16 + rloc) * ldb + kb_, &Bs[buf][(wave + 4) * 512]); \
  } while (0)

  STAGE2(0, 0);
  STAGE2(1, 1);
  asm volatile("s_waitcnt vmcnt(4)" ::: "memory");
  __builtin_amdgcn_s_barrier();
  __builtin_amdgcn_sched_barrier(0);

  for (int kt = 0; kt < ktiles; ++kt) {
    const int cur = kt % 3;
    const bool st = (kt + 2 < ktiles);
    if (st) STAGE2((kt + 2) % 3, kt + 2);

    bf16x8 af[4], bfv[4];
#pragma unroll
    for (int mi = 0; mi < 4; ++mi)
      af[mi] = *reinterpret_cast<const bf16x8*>(&As[cur][fA + mi * 512]);
#pragma unroll
    for (int ni = 0; ni < 4; ++ni)
      bfv[ni] = *reinterpret_cast<const bf16x8*>(&Bs[cur][fB + ni * 512]);

    __builtin_amdgcn_s_setprio(1);
#pragma unroll
    for (int mi = 0; mi < 4; ++mi)
#pragma unroll
      for (int ni = 0; ni < 4; ++ni)
        acc[mi][ni] = __builtin_amdgcn_mfma_f32_16x16x32_bf16(af[mi], bfv[ni], acc[mi][ni], 0, 0, 0);
    __builtin_amdgcn_s_setprio(0);

    if (st) { asm volatile("s_waitcnt vmcnt(4)" ::: "memory"); }
    else    { asm volatile("s_waitcnt vmcnt(0)" ::: "memory"); }
    __builtin_amdgcn_s_barrier();
    __builtin_amdgcn_sched_barrier(0);
  }
#undef STAGE2

  const int row0 = wr * 64, col0 = wc * 64;
  if (is_score) {
    // P = exp(|s|/32) (0 above diag), bf16-rounded; per-row partial sums
#pragma unroll
    for (int mi = 0; mi < 4; ++mi) {
#pragma unroll
      for (int r = 0; r < 4; ++r) {
        const int gi = ti * 128 + row0 + mi * 16 + (lane >> 4) * 4 + r;
        float ps = 0.f;
#pragma unroll
        for (int ni = 0; ni < 4; ++ni) {
          const int gj = tj * 128 + col0 + ni * 16 + (lane & 15);
          float p = (gj > gi) ? 0.f : __expf(fabsf(acc[mi][ni][r]) * 0.03125f);
          unsigned short us = f2bf(p);
          Sc[(size_t)bz * SDIM * SDIM + (size_t)gi * SDIM + gj] = us;
          ps += bf2f(us);
        }
        ps += __shfl_xor(ps, 1);
        ps += __shfl_xor(ps, 2);
        ps += __shfl_xor(ps, 4);
        ps += __shfl_xor(ps, 8);
        if ((lane & 15) == 0)
          partial[((size_t)bz * SDIM + gi) * 32 + tj * 2 + wc] = ps;
      }
    }
  } else {
    // VWo^T tile: [d, s] row-major, ld = SDIM
#pragma unroll
    for (int mi = 0; mi < 4; ++mi) {
#pragma unroll
      for (int ni = 0; ni < 4; ++ni) {
#pragma unroll
        for (int r = 0; r < 4; ++r) {
          const int gd = ti * 128 + row0 + mi * 16 + (lane >> 4) * 4 + r;
          const int gs = tj * 128 + col0 + ni * 16 + (lane & 15);
          VWo_t[(size_t)bz * DDIM * SDIM + (size_t)gd * SDIM + gs] = f2bf(acc[mi][ni][r]);
        }
      }
    }
  }
}

// ---------------- host launch ----------------
extern "C" void kernel_launch(void* const* d_in, const int* in_sizes, int n_in,
                              void* d_out, int out_size, void* d_ws, size_t ws_size,
                              hipStream_t stream) {
  const float* x  = (const float*)d_in[0];
  const float* Wq = (const float*)d_in[1];
  const float* bq = (const float*)d_in[2];
  const float* Wk = (const float*)d_in[3];
  const float* bk = (const float*)d_in[4];
  const float* Wv = (const float*)d_in[5];
  const float* bv = (const float*)d_in[6];
  const float* Wo = (const float*)d_in[7];
  const float* bo = (const float*)d_in[8];
  float* out = (float*)d_out;

  const size_t NTOK = (size_t)BATCH * SDIM;       // 8192
  unsigned short* ws = (unsigned short*)d_ws;
  unsigned short* xb   = ws;                          // [8192,1024]
  unsigned short* wqkv = xb + NTOK * DDIM;            // [3072,1024]
  unsigned short* wo   = wqkv + (size_t)QKVN * DDIM;  // [1024,1024]
  unsigned short* QKVb = wo + (size_t)DDIM * DDIM;    // [8192,3072]
  unsigned short* VWot = QKVb + NTOK * QKVN;          // [B,1024,2048] = (V@Wo^T)^T
  unsigned short* Sc   = VWot + NTOK * DDIM;          // [B,2048,2048] = P (exp)
  float* partial = (float*)(Sc + (size_t)BATCH * SDIM * SDIM);  // [8192][32]

  // all converts in one dispatch (dest regions contiguous from ws)
  cvt_all<<<2048, 256, 0, stream>>>(x, Wq, Wk, Wv, Wo, xb);

  // fused QKV projection -> QKVb [8192, 3072]  (1D grid, XCD ti-band decode)
  gemm_kernel<0><<<1536, 256, 0, stream>>>(xb, wqkv, bq, bk, bv, nullptr, QKVb);

  // scores (P=exp, partials) || VWo^T  (1D grid, XCD batch-half decode)
  attn_prep<<<1056, 256, 0, stream>>>(QKVb, wo, partial, Sc, VWot);

  // out = rowInv * (P @ VWo^T) + bo  (1D grid, XCD batch-half + balanced ti)
  gemm_kernel<1><<<512, 256, 0, stream>>>(Sc, VWot, bo, nullptr, nullptr,
                                          partial, out);
}